// Round 7
// baseline (141.949 us; speedup 1.0000x reference)
//
#include <hip/hip_runtime.h>
#include <hip/hip_bf16.h>

typedef unsigned short u16;
typedef __attribute__((ext_vector_type(8))) short frag_ab;   // 8 bf16 (4 VGPRs)
typedef __attribute__((ext_vector_type(4))) float f32x4;     // 4 fp32 acc
typedef _Float16 f16;
typedef __attribute__((ext_vector_type(4))) _Float16 f16x4;  // 4 f16 (2 VGPRs)

#define LOG2E 1.44269504088896f

__device__ __forceinline__ float fast_exp2(float x) {
    return __builtin_amdgcn_exp2f(x);   // v_exp_f32 (D = 2^S0)
}

__device__ __forceinline__ void gload_lds16(const u16* g, u16* s) {
    __builtin_amdgcn_global_load_lds((const __attribute__((address_space(1))) void*)g,
                                     (__attribute__((address_space(3))) void*)s, 16, 0, 0);
}

// ---------------------------------------------------------------------------
// 64x128 B^T GEMM mainloop, K=512, 2-phase pipelined (R2 structure, proven).
// ---------------------------------------------------------------------------
__device__ __forceinline__ void gemm64x128_bt_mainloop(
    const u16* __restrict__ A, const u16* __restrict__ B,
    int m0, int n0, f32x4 acc[2][4], u16* lds)
{
    const int tid = threadIdx.x;
    const int lane = tid & 63, quad = lane >> 4, l16 = lane & 15;
    const int wr = ((tid >> 7) & 1) * 32;
    const int wc = ((tid >> 6) & 1) * 64;
    const int srow = tid >> 3;
    const int scol = (tid & 7) * 8;

    u16* Asb[2] = {lds, lds + 12288};
    u16* Bsb[2] = {lds + 4096, lds + 16384};

#define STAGE_128(bi, k0) do {                                                \
        u16* As_ = Asb[bi]; u16* Bs_ = Bsb[bi];                               \
        _Pragma("unroll")                                                     \
        for (int p = 0; p < 2; ++p) {                                         \
            const int r = srow + p * 32;                                      \
            gload_lds16(A + (size_t)(m0 + r) * 512 + (k0) + scol,             \
                        As_ + r * 64 + scol);                                 \
        }                                                                     \
        _Pragma("unroll")                                                     \
        for (int p = 0; p < 4; ++p) {                                         \
            const int r = srow + p * 32;                                      \
            gload_lds16(B + (size_t)(n0 + r) * 512 + (k0) + scol,             \
                        Bs_ + r * 64 + scol);                                 \
        }                                                                     \
    } while (0)

    STAGE_128(0, 0);
    __syncthreads();
    #pragma unroll
    for (int t = 0; t < 8; ++t) {
        const int cur = t & 1;
        if (t < 7) STAGE_128(cur ^ 1, (t + 1) * 64);
        u16* Asc = Asb[cur];
        u16* Bsc = Bsb[cur];
        #pragma unroll
        for (int ks = 0; ks < 2; ++ks) {
            frag_ab a[2], b[4];
            #pragma unroll
            for (int mt = 0; mt < 2; ++mt)
                a[mt] = *(const frag_ab*)(Asc + (wr + mt * 16 + l16) * 64 + ks * 32 + quad * 8);
            #pragma unroll
            for (int nt = 0; nt < 4; ++nt)
                b[nt] = *(const frag_ab*)(Bsc + (wc + nt * 16 + l16) * 64 + ks * 32 + quad * 8);
            #pragma unroll
            for (int mt = 0; mt < 2; ++mt)
                #pragma unroll
                for (int nt = 0; nt < 4; ++nt)
                    acc[mt][nt] = __builtin_amdgcn_mfma_f32_16x16x32_bf16(a[mt], b[nt], acc[mt][nt], 0, 0, 0);
        }
        if (t < 7) __syncthreads();
    }
#undef STAGE_128
}

// ---------------------------------------------------------------------------
// 64x64 B^T GEMM mainloop, K=512, same 2-phase pipeline. LDS 32 KB.
// ---------------------------------------------------------------------------
__device__ __forceinline__ void gemm64x64_bt_mainloop(
    const u16* __restrict__ A, const u16* __restrict__ B,
    int m0, int n0, f32x4 acc[2][2], u16* lds)
{
    const int tid = threadIdx.x;
    const int lane = tid & 63, quad = lane >> 4, l16 = lane & 15;
    const int wr = ((tid >> 7) & 1) * 32;
    const int wc = ((tid >> 6) & 1) * 32;
    const int srow = tid >> 3;
    const int scol = (tid & 7) * 8;

    u16* Asb[2] = {lds, lds + 8192};
    u16* Bsb[2] = {lds + 4096, lds + 12288};

#define STAGE_64(bi, k0) do {                                                 \
        u16* As_ = Asb[bi]; u16* Bs_ = Bsb[bi];                               \
        _Pragma("unroll")                                                     \
        for (int p = 0; p < 2; ++p) {                                         \
            const int r = srow + p * 32;                                      \
            gload_lds16(A + (size_t)(m0 + r) * 512 + (k0) + scol,             \
                        As_ + r * 64 + scol);                                 \
            gload_lds16(B + (size_t)(n0 + r) * 512 + (k0) + scol,             \
                        Bs_ + r * 64 + scol);                                 \
        }                                                                     \
    } while (0)

    STAGE_64(0, 0);
    __syncthreads();
    #pragma unroll
    for (int t = 0; t < 8; ++t) {
        const int cur = t & 1;
        if (t < 7) STAGE_64(cur ^ 1, (t + 1) * 64);
        u16* Asc = Asb[cur];
        u16* Bsc = Bsb[cur];
        #pragma unroll
        for (int ks = 0; ks < 2; ++ks) {
            frag_ab a[2], b[2];
            #pragma unroll
            for (int mt = 0; mt < 2; ++mt)
                a[mt] = *(const frag_ab*)(Asc + (wr + mt * 16 + l16) * 64 + ks * 32 + quad * 8);
            #pragma unroll
            for (int nt = 0; nt < 2; ++nt)
                b[nt] = *(const frag_ab*)(Bsc + (wc + nt * 16 + l16) * 64 + ks * 32 + quad * 8);
            #pragma unroll
            for (int mt = 0; mt < 2; ++mt)
                #pragma unroll
                for (int nt = 0; nt < 2; ++nt)
                    acc[mt][nt] = __builtin_amdgcn_mfma_f32_16x16x32_bf16(a[mt], b[nt], acc[mt][nt], 0, 0, 0);
        }
        if (t < 7) __syncthreads();
    }
#undef STAGE_64
}

// ---------------------------------------------------------------------------
// Fused prep: blocks [0,2048): x transpose+cast; [2048,3072): W converts.
// ---------------------------------------------------------------------------
__global__ __launch_bounds__(256) void prep_kernel(
    const float* __restrict__ x, __hip_bfloat16* __restrict__ xs_bf,
    const float* __restrict__ Wp, const float* __restrict__ Wo,
    __hip_bfloat16* __restrict__ w_bf)
{
    __shared__ float tile[32][33];
    const int tid = threadIdx.x;
    const int id = blockIdx.x;
    if (id < 2048) {
        const int i0 = (id & 31) * 32;
        const int c0 = ((id >> 5) & 15) * 32;
        const int b  = id >> 9;
        const int tx = tid & 31, ty = tid >> 5;
        const float* xp = x + ((size_t)b * 512 + c0) * 1024 + i0;
        #pragma unroll
        for (int r = ty; r < 32; r += 8)
            tile[r][tx] = xp[(size_t)r * 1024 + tx];
        __syncthreads();
        __hip_bfloat16* op = xs_bf + ((size_t)b * 1024 + i0) * 512 + c0;
        #pragma unroll
        for (int r = ty; r < 32; r += 8)
            op[(size_t)r * 512 + tx] = __float2bfloat16(tile[tx][r]);
    } else {
        const int t = (id - 2048) * 256 + tid;
        const int i4 = t * 4;
        const float* src = (i4 < 786432) ? (Wp + i4) : (Wo + (i4 - 786432));
        const float4 v = *(const float4*)src;
        ushort4 o;
        o.x = __bfloat16_as_ushort(__float2bfloat16(v.x));
        o.y = __bfloat16_as_ushort(__float2bfloat16(v.y));
        o.z = __bfloat16_as_ushort(__float2bfloat16(v.z));
        o.w = __bfloat16_as_ushort(__float2bfloat16(v.w));
        *(ushort4*)((u16*)w_bf + i4) = o;
    }
}

// ---------------------------------------------------------------------------
// qkv^T GEMM: 64-ch x 128-pix tiles, grid (32 pix-windows, 24 ch-tiles).
// ---------------------------------------------------------------------------
__global__ __launch_bounds__(256) void qkv_gemm_kernel(
    const u16* __restrict__ Wpb, const u16* __restrict__ xsb,
    const float* __restrict__ bp,
    u16* __restrict__ Qb, u16* __restrict__ Kb, f16* __restrict__ VtT)
{
    __shared__ u16 lds[24576];      // dbuf As/Bs; reused as Tr[128][72]
    f32x4 acc[2][4];
    #pragma unroll
    for (int mt = 0; mt < 2; ++mt)
        #pragma unroll
        for (int nt = 0; nt < 4; ++nt)
            { acc[mt][nt][0]=0.f; acc[mt][nt][1]=0.f; acc[mt][nt][2]=0.f; acc[mt][nt][3]=0.f; }
    const int m0 = blockIdx.y * 64;    // ch   (y: 0..23)
    const int n0 = blockIdx.x * 128;   // pix  (x: 0..31)
    gemm64x128_bt_mainloop(Wpb, xsb, m0, n0, acc, lds);

    const int tid = threadIdx.x;
    const int lane = tid & 63, quad = lane >> 4, l16 = lane & 15;
    const int wr = ((tid >> 7) & 1) * 32, wc = ((tid >> 6) & 1) * 64;
    const int h = blockIdx.y / 3, part = blockIdx.y % 3;   // block-uniform
    const int b = blockIdx.x >> 3, ipb = (blockIdx.x & 7) * 128;
    const size_t bh = (size_t)(b * 8 + h);

    if (part < 2) {
        const float scale = (part == 0) ? (0.125f * LOG2E) : 1.0f;
        __syncthreads();            // all waves done with mainloop LDS
        u16* T = lds;               // [pix 128][ch 64 pad 72]
        #pragma unroll
        for (int nt = 0; nt < 4; ++nt) {
            const int px = wc + nt * 16 + l16;
            #pragma unroll
            for (int mt = 0; mt < 2; ++mt) {
                const int cb = m0 + wr + mt * 16 + quad * 4;
                ushort4 pk;
                pk.x = __bfloat16_as_ushort(__float2bfloat16((acc[mt][nt][0] + bp[cb + 0]) * scale));
                pk.y = __bfloat16_as_ushort(__float2bfloat16((acc[mt][nt][1] + bp[cb + 1]) * scale));
                pk.z = __bfloat16_as_ushort(__float2bfloat16((acc[mt][nt][2] + bp[cb + 2]) * scale));
                pk.w = __bfloat16_as_ushort(__float2bfloat16((acc[mt][nt][3] + bp[cb + 3]) * scale));
                *(ushort4*)&T[px * 72 + wr + mt * 16 + quad * 4] = pk;
            }
        }
        __syncthreads();
        u16* dst = (part == 0 ? Qb : Kb);
        #pragma unroll
        for (int p = 0; p < 4; ++p) {
            const int row = p * 32 + (tid >> 3);
            const int ch8 = (tid & 7) * 8;
            uint4 rv = *(uint4*)&T[row * 72 + ch8];
            *(uint4*)(dst + ((bh * 1024 + ipb + row) << 6) + ch8) = rv;
        }
    } else {
        f16* dst = VtT + bh * 65536;   // [jc 128][d 64][j8 8]
        #pragma unroll
        for (int mt = 0; mt < 2; ++mt) {
            #pragma unroll
            for (int r = 0; r < 4; ++r) {
                const int d = wr + mt * 16 + quad * 4 + r;
                const float bias = bp[m0 + d];
                #pragma unroll
                for (int nt = 0; nt < 4; ++nt) {
                    const int j = ipb + wc + nt * 16 + l16;
                    dst[(size_t)(j >> 3) * 512 + d * 8 + (j & 7)] =
                        (f16)(acc[mt][nt][r] + bias);
                }
            }
        }
    }
}

// ---------------------------------------------------------------------------
// Attention v7: 8 waves x DISJOINT 16-j windows (512 thr). Each wave covers
// ALL 64 i-rows (4 ig) of j-window w*16 within each 128-j tile — per-wave
// bytes/MFMA identical to v4 (v5/v6 lesson: attn time tracks per-block K/V
// traffic; any split that duplicates K/V loses). 16 waves/CU (4/SIMD) vs
// v4's 8 — TLP replaces ILP: NO register double-buffering (VGPR cap 128 at
// launch_bounds(512,4); bq 32 + o 64 + ka 8 + va 8 + addr fits).
// Max-free softmax => additive partials; 8-way combine via two LDS phases
// over a 4-slab buffer. LDS 71.7KB x 2 blocks = 143 <= 160.
// ---------------------------------------------------------------------------
__global__ __launch_bounds__(512, 4) void attn_kernel(
    const u16* __restrict__ Qb, const u16* __restrict__ Kb,
    const f16* __restrict__ VtT, __hip_bfloat16* __restrict__ resb)
{
    __shared__ float Opart[4][64][68];    // 69.6 KB, reused by both phases
    __shared__ float Lpart[8][4][16];     // 2 KB [w][ig][i]
    const int bh = blockIdx.x;
    const int it = blockIdx.y;            // 64-row i tile, 0..15
    const int tid = threadIdx.x;
    const int w = tid >> 6, lane = tid & 63, quad = lane >> 4, l16 = lane & 15;

    const u16* Qp = Qb + (size_t)bh * 65536;
    const u16* Kp = Kb + (size_t)bh * 65536;
    const f16* Vp = VtT + (size_t)bh * 65536;

    frag_ab bq[4][2];
    #pragma unroll
    for (int ig = 0; ig < 4; ++ig) {
        const u16* qptr = Qp + (size_t)(it * 64 + ig * 16 + l16) * 64 + quad * 8;
        bq[ig][0] = *(const frag_ab*)(qptr);
        bq[ig][1] = *(const frag_ab*)(qptr + 32);
    }

    f32x4 o[4][4];
    #pragma unroll
    for (int ig = 0; ig < 4; ++ig)
        #pragma unroll
        for (int dt = 0; dt < 4; ++dt)
            { o[ig][dt][0]=0.f; o[ig][dt][1]=0.f; o[ig][dt][2]=0.f; o[ig][dt][3]=0.f; }
    float l_acc[4] = {0.f, 0.f, 0.f, 0.f};

    // K frag: rows w*16 + l16 (16-j window), cols quad*8 (+32).
    const u16* kbase = Kp + (size_t)(w * 16 + l16) * 64 + quad * 8;
    // V frag: j = w*16 + quad*4 + e -> jc = w*2 + (quad>>1), j8 = (quad&1)*4+e;
    // d = dt*16 + l16.
    const f16* vbase = Vp + (size_t)(w * 2 + (quad >> 1)) * 512 + l16 * 8 + (quad & 1) * 4;

    #pragma unroll
    for (int jt = 0; jt < 8; ++jt) {
        frag_ab ka[2];
        {
            const u16* kp_ = kbase + (size_t)jt * 8192;
            ka[0] = *(const frag_ab*)(kp_);
            ka[1] = *(const frag_ab*)(kp_ + 32);
        }
        f16x4 va[4];
        {
            const f16* vp_ = vbase + (size_t)jt * 8192;
            #pragma unroll
            for (int dt = 0; dt < 4; ++dt)
                va[dt] = *(const f16x4*)(vp_ + dt * 128);
        }
        #pragma unroll
        for (int ig = 0; ig < 4; ++ig) {
            f32x4 st = {0.f, 0.f, 0.f, 0.f};
            __builtin_amdgcn_s_setprio(1);
            st = __builtin_amdgcn_mfma_f32_16x16x32_bf16(ka[0], bq[ig][0], st, 0, 0, 0);
            st = __builtin_amdgcn_mfma_f32_16x16x32_bf16(ka[1], bq[ig][1], st, 0, 0, 0);
            __builtin_amdgcn_s_setprio(0);
            f16x4 p;
            float s = 0.f;
            #pragma unroll
            for (int r = 0; r < 4; ++r) {
                const float e = fast_exp2(st[r]);
                s += e;
                p[r] = (f16)e;
            }
            l_acc[ig] += s;
            __builtin_amdgcn_s_setprio(1);
            #pragma unroll
            for (int dt = 0; dt < 4; ++dt)
                o[ig][dt] = __builtin_amdgcn_mfma_f32_16x16x16f16(va[dt], p, o[ig][dt], 0, 0, 0);
            __builtin_amdgcn_s_setprio(0);
        }
    }

    // Per-lane l_acc covers js {w*16 + quad*4 + r}; reduce across quads -> per-i.
    #pragma unroll
    for (int ig = 0; ig < 4; ++ig) {
        l_acc[ig] += __shfl_xor(l_acc[ig], 16);
        l_acc[ig] += __shfl_xor(l_acc[ig], 32);
    }
    if (lane < 16) {
        #pragma unroll
        for (int ig = 0; ig < 4; ++ig)
            Lpart[w][ig][lane] = l_acc[ig];
    }

    const int bb = bh >> 3, hh = bh & 7;
    const int il = tid >> 3, d0 = (tid & 7) * 8;   // il 0..63, d0 0..56

    // Phase A: waves 0-3 publish their full [64][64] partial.
    __syncthreads();
    if (w < 4) {
        #pragma unroll
        for (int ig = 0; ig < 4; ++ig)
            #pragma unroll
            for (int dt = 0; dt < 4; ++dt)
                *(f32x4*)&Opart[w][ig * 16 + l16][dt * 16 + quad * 4] = o[ig][dt];
    }
    __syncthreads();
    f32x4 sa = *(const f32x4*)&Opart[0][il][d0];
    f32x4 sb = *(const f32x4*)&Opart[0][il][d0 + 4];
    #pragma unroll
    for (int ww = 1; ww < 4; ++ww) {
        sa += *(const f32x4*)&Opart[ww][il][d0];
        sb += *(const f32x4*)&Opart[ww][il][d0 + 4];
    }
    // Phase B: waves 4-7 overwrite the same slabs.
    __syncthreads();
    if (w >= 4) {
        #pragma unroll
        for (int ig = 0; ig < 4; ++ig)
            #pragma unroll
            for (int dt = 0; dt < 4; ++dt)
                *(f32x4*)&Opart[w - 4][ig * 16 + l16][dt * 16 + quad * 4] = o[ig][dt];
    }
    __syncthreads();
    #pragma unroll
    for (int ww = 0; ww < 4; ++ww) {
        sa += *(const f32x4*)&Opart[ww][il][d0];
        sb += *(const f32x4*)&Opart[ww][il][d0 + 4];
    }

    const int ig = il >> 4;
    float lsum = 0.f;
    #pragma unroll
    for (int ww = 0; ww < 8; ++ww)
        lsum += Lpart[ww][ig][il & 15];
    const float linv = 1.f / lsum;
    u16 pk[8];
    #pragma unroll
    for (int e = 0; e < 4; ++e) {
        pk[e]     = __bfloat16_as_ushort(__float2bfloat16(sa[e] * linv));
        pk[e + 4] = __bfloat16_as_ushort(__float2bfloat16(sb[e] * linv));
    }
    u16* orow = (u16*)resb +
        ((size_t)(bb * 1024 + it * 64 + il)) * 512 + hh * 64 + d0;
    *(uint4*)orow = *(uint4*)pk;
}

// ---------------------------------------------------------------------------
// out^T GEMM: 64x64 tiles, grid 8x64 = 512 blocks = 2/CU. LDS 32 KB dbuf.
// ---------------------------------------------------------------------------
__global__ __launch_bounds__(256) void out_gemm_kernel(
    const u16* __restrict__ Wob, const u16* __restrict__ resb,
    const float* __restrict__ bo, const float* __restrict__ x,
    float* __restrict__ out)
{
    __shared__ u16 lds[16384];
    f32x4 acc[2][2];
    #pragma unroll
    for (int mt = 0; mt < 2; ++mt)
        #pragma unroll
        for (int nt = 0; nt < 2; ++nt)
            { acc[mt][nt][0]=0.f; acc[mt][nt][1]=0.f; acc[mt][nt][2]=0.f; acc[mt][nt][3]=0.f; }
    const int m0 = blockIdx.x * 64;   // c
    const int n0 = blockIdx.y * 64;   // pix
    gemm64x64_bt_mainloop(Wob, resb, m0, n0, acc, lds);

    const int tid = threadIdx.x;
    const int lane = tid & 63, quad = lane >> 4, l16 = lane & 15;
    const int wr = ((tid >> 7) & 1) * 32, wc = ((tid >> 6) & 1) * 32;
    #pragma unroll
    for (int nt = 0; nt < 2; ++nt) {
        const int pix = n0 + wc + nt * 16 + l16;
        const int b = pix >> 10, ip = pix & 1023;
        #pragma unroll
        for (int mt = 0; mt < 2; ++mt) {
            #pragma unroll
            for (int r = 0; r < 4; ++r) {
                const int c = m0 + wr + mt * 16 + quad * 4 + r;
                const size_t oidx = (((size_t)b * 512 + c) << 10) + ip;
                out[oidx] = acc[mt][nt][r] + bo[c] + x[oidx];
            }
        }
    }
}

// ---------------------------------------------------------------------------
extern "C" void kernel_launch(void* const* d_in, const int* in_sizes, int n_in,
                              void* d_out, int out_size, void* d_ws, size_t ws_size,
                              hipStream_t stream)
{
    const float* x  = (const float*)d_in[0];   // [4,512,32,32]
    const float* Wp = (const float*)d_in[1];   // [1536,512]
    const float* bp = (const float*)d_in[2];   // [1536]
    const float* Wo = (const float*)d_in[3];   // [512,512]
    const float* bo = (const float*)d_in[4];   // [512]
    float* out = (float*)d_out;

    char* ws = (char*)d_ws;
    size_t off = 0;
    auto carve = [&](size_t bytes) -> void* {
        void* ptr = ws + off;
        off += (bytes + 255) & ~(size_t)255;
        return ptr;
    };
    __hip_bfloat16* xs_bf = (__hip_bfloat16*)carve((size_t)4096 * 512 * 2);
    __hip_bfloat16* Wp_bf = (__hip_bfloat16*)carve((size_t)1536 * 512 * 2);  // Wo_bf contiguous after
    __hip_bfloat16* Wo_bf = (__hip_bfloat16*)carve((size_t)512 * 512 * 2);
    u16*            Qb    = (u16*)carve((size_t)32 * 1024 * 64 * 2);
    u16*            Kb    = (u16*)carve((size_t)32 * 1024 * 64 * 2);
    f16*            VtT   = (f16*)carve((size_t)32 * 1024 * 64 * 2);
    __hip_bfloat16* resb  = (__hip_bfloat16*)carve((size_t)4096 * 512 * 2);

    prep_kernel<<<dim3(3072), 256, 0, stream>>>(x, xs_bf, Wp, Wo, Wp_bf);
    qkv_gemm_kernel<<<dim3(32, 24), 256, 0, stream>>>(
        (const u16*)Wp_bf, (const u16*)xs_bf, bp, Qb, Kb, VtT);
    attn_kernel<<<dim3(32, 16), 512, 0, stream>>>(Qb, Kb, VtT, resb);
    out_gemm_kernel<<<dim3(8, 64), 256, 0, stream>>>(
        (const u16*)Wo_bf, (const u16*)resb, bo, x, out);
    (void)Wo_bf; (void)ws_size; (void)in_sizes; (void)n_in; (void)out_size;
}

// Round 8
// 111.344 us; speedup vs baseline: 1.2749x; 1.2749x over previous
//
#include <hip/hip_runtime.h>
#include <hip/hip_bf16.h>

typedef unsigned short u16;
typedef __attribute__((ext_vector_type(8))) short frag_ab;   // 8 bf16 (4 VGPRs)
typedef __attribute__((ext_vector_type(4))) float f32x4;     // 4 fp32 acc
typedef _Float16 f16;
typedef __attribute__((ext_vector_type(4))) _Float16 f16x4;  // 4 f16 (2 VGPRs)

#define LOG2E 1.44269504088896f

__device__ __forceinline__ float fast_exp2(float x) {
    return __builtin_amdgcn_exp2f(x);   // v_exp_f32 (D = 2^S0)
}

__device__ __forceinline__ void gload_lds16(const u16* g, u16* s) {
    __builtin_amdgcn_global_load_lds((const __attribute__((address_space(1))) void*)g,
                                     (__attribute__((address_space(3))) void*)s, 16, 0, 0);
}

// ---------------------------------------------------------------------------
// 64x128 B^T GEMM mainloop, K=512, 2-phase pipelined (R2 structure, proven).
// ---------------------------------------------------------------------------
__device__ __forceinline__ void gemm64x128_bt_mainloop(
    const u16* __restrict__ A, const u16* __restrict__ B,
    int m0, int n0, f32x4 acc[2][4], u16* lds)
{
    const int tid = threadIdx.x;
    const int lane = tid & 63, quad = lane >> 4, l16 = lane & 15;
    const int wr = ((tid >> 7) & 1) * 32;
    const int wc = ((tid >> 6) & 1) * 64;
    const int srow = tid >> 3;
    const int scol = (tid & 7) * 8;

    u16* Asb[2] = {lds, lds + 12288};
    u16* Bsb[2] = {lds + 4096, lds + 16384};

#define STAGE_128(bi, k0) do {                                                \
        u16* As_ = Asb[bi]; u16* Bs_ = Bsb[bi];                               \
        _Pragma("unroll")                                                     \
        for (int p = 0; p < 2; ++p) {                                         \
            const int r = srow + p * 32;                                      \
            gload_lds16(A + (size_t)(m0 + r) * 512 + (k0) + scol,             \
                        As_ + r * 64 + scol);                                 \
        }                                                                     \
        _Pragma("unroll")                                                     \
        for (int p = 0; p < 4; ++p) {                                         \
            const int r = srow + p * 32;                                      \
            gload_lds16(B + (size_t)(n0 + r) * 512 + (k0) + scol,             \
                        Bs_ + r * 64 + scol);                                 \
        }                                                                     \
    } while (0)

    STAGE_128(0, 0);
    __syncthreads();
    #pragma unroll
    for (int t = 0; t < 8; ++t) {
        const int cur = t & 1;
        if (t < 7) STAGE_128(cur ^ 1, (t + 1) * 64);
        u16* Asc = Asb[cur];
        u16* Bsc = Bsb[cur];
        #pragma unroll
        for (int ks = 0; ks < 2; ++ks) {
            frag_ab a[2], b[4];
            #pragma unroll
            for (int mt = 0; mt < 2; ++mt)
                a[mt] = *(const frag_ab*)(Asc + (wr + mt * 16 + l16) * 64 + ks * 32 + quad * 8);
            #pragma unroll
            for (int nt = 0; nt < 4; ++nt)
                b[nt] = *(const frag_ab*)(Bsc + (wc + nt * 16 + l16) * 64 + ks * 32 + quad * 8);
            #pragma unroll
            for (int mt = 0; mt < 2; ++mt)
                #pragma unroll
                for (int nt = 0; nt < 4; ++nt)
                    acc[mt][nt] = __builtin_amdgcn_mfma_f32_16x16x32_bf16(a[mt], b[nt], acc[mt][nt], 0, 0, 0);
        }
        if (t < 7) __syncthreads();
    }
#undef STAGE_128
}

// ---------------------------------------------------------------------------
// 64x64 B^T GEMM mainloop, K=512, same 2-phase pipeline. LDS 32 KB.
// ---------------------------------------------------------------------------
__device__ __forceinline__ void gemm64x64_bt_mainloop(
    const u16* __restrict__ A, const u16* __restrict__ B,
    int m0, int n0, f32x4 acc[2][2], u16* lds)
{
    const int tid = threadIdx.x;
    const int lane = tid & 63, quad = lane >> 4, l16 = lane & 15;
    const int wr = ((tid >> 7) & 1) * 32;
    const int wc = ((tid >> 6) & 1) * 32;
    const int srow = tid >> 3;
    const int scol = (tid & 7) * 8;

    u16* Asb[2] = {lds, lds + 8192};
    u16* Bsb[2] = {lds + 4096, lds + 12288};

#define STAGE_64(bi, k0) do {                                                 \
        u16* As_ = Asb[bi]; u16* Bs_ = Bsb[bi];                               \
        _Pragma("unroll")                                                     \
        for (int p = 0; p < 2; ++p) {                                         \
            const int r = srow + p * 32;                                      \
            gload_lds16(A + (size_t)(m0 + r) * 512 + (k0) + scol,             \
                        As_ + r * 64 + scol);                                 \
            gload_lds16(B + (size_t)(n0 + r) * 512 + (k0) + scol,             \
                        Bs_ + r * 64 + scol);                                 \
        }                                                                     \
    } while (0)

    STAGE_64(0, 0);
    __syncthreads();
    #pragma unroll
    for (int t = 0; t < 8; ++t) {
        const int cur = t & 1;
        if (t < 7) STAGE_64(cur ^ 1, (t + 1) * 64);
        u16* Asc = Asb[cur];
        u16* Bsc = Bsb[cur];
        #pragma unroll
        for (int ks = 0; ks < 2; ++ks) {
            frag_ab a[2], b[2];
            #pragma unroll
            for (int mt = 0; mt < 2; ++mt)
                a[mt] = *(const frag_ab*)(Asc + (wr + mt * 16 + l16) * 64 + ks * 32 + quad * 8);
            #pragma unroll
            for (int nt = 0; nt < 2; ++nt)
                b[nt] = *(const frag_ab*)(Bsc + (wc + nt * 16 + l16) * 64 + ks * 32 + quad * 8);
            #pragma unroll
            for (int mt = 0; mt < 2; ++mt)
                #pragma unroll
                for (int nt = 0; nt < 2; ++nt)
                    acc[mt][nt] = __builtin_amdgcn_mfma_f32_16x16x32_bf16(a[mt], b[nt], acc[mt][nt], 0, 0, 0);
        }
        if (t < 7) __syncthreads();
    }
#undef STAGE_64
}

// ---------------------------------------------------------------------------
// Fused prep: blocks [0,2048): x transpose+cast; [2048,3072): W converts.
// ---------------------------------------------------------------------------
__global__ __launch_bounds__(256) void prep_kernel(
    const float* __restrict__ x, __hip_bfloat16* __restrict__ xs_bf,
    const float* __restrict__ Wp, const float* __restrict__ Wo,
    __hip_bfloat16* __restrict__ w_bf)
{
    __shared__ float tile[32][33];
    const int tid = threadIdx.x;
    const int id = blockIdx.x;
    if (id < 2048) {
        const int i0 = (id & 31) * 32;
        const int c0 = ((id >> 5) & 15) * 32;
        const int b  = id >> 9;
        const int tx = tid & 31, ty = tid >> 5;
        const float* xp = x + ((size_t)b * 512 + c0) * 1024 + i0;
        #pragma unroll
        for (int r = ty; r < 32; r += 8)
            tile[r][tx] = xp[(size_t)r * 1024 + tx];
        __syncthreads();
        __hip_bfloat16* op = xs_bf + ((size_t)b * 1024 + i0) * 512 + c0;
        #pragma unroll
        for (int r = ty; r < 32; r += 8)
            op[(size_t)r * 512 + tx] = __float2bfloat16(tile[tx][r]);
    } else {
        const int t = (id - 2048) * 256 + tid;
        const int i4 = t * 4;
        const float* src = (i4 < 786432) ? (Wp + i4) : (Wo + (i4 - 786432));
        const float4 v = *(const float4*)src;
        ushort4 o;
        o.x = __bfloat16_as_ushort(__float2bfloat16(v.x));
        o.y = __bfloat16_as_ushort(__float2bfloat16(v.y));
        o.z = __bfloat16_as_ushort(__float2bfloat16(v.z));
        o.w = __bfloat16_as_ushort(__float2bfloat16(v.w));
        *(ushort4*)((u16*)w_bf + i4) = o;
    }
}

// ---------------------------------------------------------------------------
// qkv^T GEMM: 64-ch x 128-pix tiles, grid (32 pix-windows, 24 ch-tiles).
// ---------------------------------------------------------------------------
__global__ __launch_bounds__(256) void qkv_gemm_kernel(
    const u16* __restrict__ Wpb, const u16* __restrict__ xsb,
    const float* __restrict__ bp,
    u16* __restrict__ Qb, u16* __restrict__ Kb, f16* __restrict__ VtT)
{
    __shared__ u16 lds[24576];      // dbuf As/Bs; reused as Tr[128][72]
    f32x4 acc[2][4];
    #pragma unroll
    for (int mt = 0; mt < 2; ++mt)
        #pragma unroll
        for (int nt = 0; nt < 4; ++nt)
            { acc[mt][nt][0]=0.f; acc[mt][nt][1]=0.f; acc[mt][nt][2]=0.f; acc[mt][nt][3]=0.f; }
    const int m0 = blockIdx.y * 64;    // ch   (y: 0..23)
    const int n0 = blockIdx.x * 128;   // pix  (x: 0..31)
    gemm64x128_bt_mainloop(Wpb, xsb, m0, n0, acc, lds);

    const int tid = threadIdx.x;
    const int lane = tid & 63, quad = lane >> 4, l16 = lane & 15;
    const int wr = ((tid >> 7) & 1) * 32, wc = ((tid >> 6) & 1) * 64;
    const int h = blockIdx.y / 3, part = blockIdx.y % 3;   // block-uniform
    const int b = blockIdx.x >> 3, ipb = (blockIdx.x & 7) * 128;
    const size_t bh = (size_t)(b * 8 + h);

    if (part < 2) {
        const float scale = (part == 0) ? (0.125f * LOG2E) : 1.0f;
        __syncthreads();            // all waves done with mainloop LDS
        u16* T = lds;               // [pix 128][ch 64 pad 72]
        #pragma unroll
        for (int nt = 0; nt < 4; ++nt) {
            const int px = wc + nt * 16 + l16;
            #pragma unroll
            for (int mt = 0; mt < 2; ++mt) {
                const int cb = m0 + wr + mt * 16 + quad * 4;
                ushort4 pk;
                pk.x = __bfloat16_as_ushort(__float2bfloat16((acc[mt][nt][0] + bp[cb + 0]) * scale));
                pk.y = __bfloat16_as_ushort(__float2bfloat16((acc[mt][nt][1] + bp[cb + 1]) * scale));
                pk.z = __bfloat16_as_ushort(__float2bfloat16((acc[mt][nt][2] + bp[cb + 2]) * scale));
                pk.w = __bfloat16_as_ushort(__float2bfloat16((acc[mt][nt][3] + bp[cb + 3]) * scale));
                *(ushort4*)&T[px * 72 + wr + mt * 16 + quad * 4] = pk;
            }
        }
        __syncthreads();
        u16* dst = (part == 0 ? Qb : Kb);
        #pragma unroll
        for (int p = 0; p < 4; ++p) {
            const int row = p * 32 + (tid >> 3);
            const int ch8 = (tid & 7) * 8;
            uint4 rv = *(uint4*)&T[row * 72 + ch8];
            *(uint4*)(dst + ((bh * 1024 + ipb + row) << 6) + ch8) = rv;
        }
    } else {
        f16* dst = VtT + bh * 65536;   // [jc 128][d 64][j8 8]
        #pragma unroll
        for (int mt = 0; mt < 2; ++mt) {
            #pragma unroll
            for (int r = 0; r < 4; ++r) {
                const int d = wr + mt * 16 + quad * 4 + r;
                const float bias = bp[m0 + d];
                #pragma unroll
                for (int nt = 0; nt < 4; ++nt) {
                    const int j = ipb + wc + nt * 16 + l16;
                    dst[(size_t)(j >> 3) * 512 + d * 8 + (j & 7)] =
                        (f16)(acc[mt][nt][r] + bias);
                }
            }
        }
    }
}

// ---------------------------------------------------------------------------
// Attention v8: v4 geometry (proven traffic/register-feasible optimum:
// 512 blocks x 4 waves, disjoint 32-j window per wave, launch_bounds(256,2))
// with K/V prefetch deepened 2->3 (grid-limited to 2 blocks/CU, so VGPR cap
// is 256 — the extra ~32 VGPR are free; v7 showed 8-wave variants spill).
// Buffer rotation fully static (rule #20). setprio(1) around MFMA (T5).
// ---------------------------------------------------------------------------
__global__ __launch_bounds__(256, 2) void attn_kernel(
    const u16* __restrict__ Qb, const u16* __restrict__ Kb,
    const f16* __restrict__ VtT, __hip_bfloat16* __restrict__ resb)
{
    __shared__ float Opart[4][32][68];    // 34.8 KB combine staging
    __shared__ float Lpart[4][4][16];     // 1 KB [w][ig][i]
    const int bh = blockIdx.x;
    const int it = blockIdx.y;            // 64-row i tile, 0..15
    const int tid = threadIdx.x;
    const int w = tid >> 6, lane = tid & 63, quad = lane >> 4, l16 = lane & 15;

    const u16* Qp = Qb + (size_t)bh * 65536;
    const u16* Kp = Kb + (size_t)bh * 65536;
    const f16* Vp = VtT + (size_t)bh * 65536;

    frag_ab bq[4][2];
    #pragma unroll
    for (int ig = 0; ig < 4; ++ig) {
        const u16* qptr = Qp + (size_t)(it * 64 + ig * 16 + l16) * 64 + quad * 8;
        bq[ig][0] = *(const frag_ab*)(qptr);
        bq[ig][1] = *(const frag_ab*)(qptr + 32);
    }

    f32x4 o[4][4];
    #pragma unroll
    for (int ig = 0; ig < 4; ++ig)
        #pragma unroll
        for (int dt = 0; dt < 4; ++dt)
            { o[ig][dt][0]=0.f; o[ig][dt][1]=0.f; o[ig][dt][2]=0.f; o[ig][dt][3]=0.f; }
    float l_acc[4] = {0.f, 0.f, 0.f, 0.f};

    const u16* kbase = Kp + (size_t)(w * 32 + l16) * 64 + quad * 8;
    const f16* vbase = Vp + (size_t)(w * 4 + (quad >> 1)) * 512 + l16 * 8 + (quad & 1) * 4;

#define LOADKV(JT, KA, VA) do {                                              \
        const u16* kp_ = kbase + (size_t)(JT) * 8192;                        \
        KA[0][0] = *(const frag_ab*)(kp_);                                   \
        KA[0][1] = *(const frag_ab*)(kp_ + 32);                              \
        KA[1][0] = *(const frag_ab*)(kp_ + 1024);                            \
        KA[1][1] = *(const frag_ab*)(kp_ + 1056);                            \
        const f16* vp_ = vbase + (size_t)(JT) * 8192;                        \
        _Pragma("unroll")                                                    \
        for (int dt_ = 0; dt_ < 4; ++dt_) {                                  \
            VA[dt_][0] = *(const f16x4*)(vp_ + dt_ * 128);                   \
            VA[dt_][1] = *(const f16x4*)(vp_ + 1024 + dt_ * 128);            \
        }                                                                    \
    } while (0)

#define COMPUTE(KA, VA) do {                                                 \
        _Pragma("unroll")                                                    \
        for (int ig = 0; ig < 4; ++ig) {                                     \
            f32x4 st0 = {0.f, 0.f, 0.f, 0.f}, st1 = {0.f, 0.f, 0.f, 0.f};    \
            __builtin_amdgcn_s_setprio(1);                                   \
            st0 = __builtin_amdgcn_mfma_f32_16x16x32_bf16(KA[0][0], bq[ig][0], st0, 0, 0, 0); \
            st0 = __builtin_amdgcn_mfma_f32_16x16x32_bf16(KA[0][1], bq[ig][1], st0, 0, 0, 0); \
            st1 = __builtin_amdgcn_mfma_f32_16x16x32_bf16(KA[1][0], bq[ig][0], st1, 0, 0, 0); \
            st1 = __builtin_amdgcn_mfma_f32_16x16x32_bf16(KA[1][1], bq[ig][1], st1, 0, 0, 0); \
            __builtin_amdgcn_s_setprio(0);                                   \
            f16x4 p0, p1;                                                    \
            float s = 0.f;                                                   \
            _Pragma("unroll")                                                \
            for (int r = 0; r < 4; ++r) {                                    \
                const float e0 = fast_exp2(st0[r]);                          \
                const float e1 = fast_exp2(st1[r]);                          \
                s += e0 + e1;                                                \
                p0[r] = (f16)e0;                                             \
                p1[r] = (f16)e1;                                             \
            }                                                                \
            l_acc[ig] += s;                                                  \
            __builtin_amdgcn_s_setprio(1);                                   \
            _Pragma("unroll")                                                \
            for (int dt = 0; dt < 4; ++dt) {                                 \
                o[ig][dt] = __builtin_amdgcn_mfma_f32_16x16x16f16(VA[dt][0], p0, o[ig][dt], 0, 0, 0); \
                o[ig][dt] = __builtin_amdgcn_mfma_f32_16x16x16f16(VA[dt][1], p1, o[ig][dt], 0, 0, 0); \
            }                                                                \
            __builtin_amdgcn_s_setprio(0);                                   \
        }                                                                    \
    } while (0)

    frag_ab kaA[2][2], kaB[2][2], kaC[2][2];
    f16x4 vaA[4][2], vaB[4][2], vaC[4][2];
    // 3-deep static rotation over 8 jt steps:
    LOADKV(0, kaA, vaA);
    LOADKV(1, kaB, vaB);
    LOADKV(2, kaC, vaC);
    COMPUTE(kaA, vaA);               // jt 0
    LOADKV(3, kaA, vaA);
    COMPUTE(kaB, vaB);               // jt 1
    LOADKV(4, kaB, vaB);
    COMPUTE(kaC, vaC);               // jt 2
    LOADKV(5, kaC, vaC);
    COMPUTE(kaA, vaA);               // jt 3
    LOADKV(6, kaA, vaA);
    COMPUTE(kaB, vaB);               // jt 4
    LOADKV(7, kaB, vaB);
    COMPUTE(kaC, vaC);               // jt 5
    COMPUTE(kaA, vaA);               // jt 6
    COMPUTE(kaB, vaB);               // jt 7
#undef LOADKV
#undef COMPUTE

    #pragma unroll
    for (int ig = 0; ig < 4; ++ig) {
        l_acc[ig] += __shfl_xor(l_acc[ig], 16);
        l_acc[ig] += __shfl_xor(l_acc[ig], 32);
    }
    if (lane < 16) {
        #pragma unroll
        for (int ig = 0; ig < 4; ++ig)
            Lpart[w][ig][lane] = l_acc[ig];
    }

    const int bb = bh >> 3, hh = bh & 7;
    const int il = tid >> 3, d0 = (tid & 7) * 8;
    #pragma unroll
    for (int ph = 0; ph < 2; ++ph) {
        __syncthreads();
        #pragma unroll
        for (int g = 0; g < 2; ++g) {
            const int ig = ph * 2 + g;
            #pragma unroll
            for (int dt = 0; dt < 4; ++dt)
                *(f32x4*)&Opart[w][g * 16 + l16][dt * 16 + quad * 4] = o[ig][dt];
        }
        __syncthreads();
        f32x4 sa = *(const f32x4*)&Opart[0][il][d0];
        f32x4 sb = *(const f32x4*)&Opart[0][il][d0 + 4];
        #pragma unroll
        for (int ww = 1; ww < 4; ++ww) {
            sa += *(const f32x4*)&Opart[ww][il][d0];
            sb += *(const f32x4*)&Opart[ww][il][d0 + 4];
        }
        const int ig = ph * 2 + (il >> 4);
        const float linv = 1.f / (Lpart[0][ig][il & 15] + Lpart[1][ig][il & 15] +
                                  Lpart[2][ig][il & 15] + Lpart[3][ig][il & 15]);
        u16 pk[8];
        #pragma unroll
        for (int e = 0; e < 4; ++e) {
            pk[e]     = __bfloat16_as_ushort(__float2bfloat16(sa[e] * linv));
            pk[e + 4] = __bfloat16_as_ushort(__float2bfloat16(sb[e] * linv));
        }
        u16* orow = (u16*)resb +
            ((size_t)(bb * 1024 + it * 64 + ph * 32 + il)) * 512 + hh * 64 + d0;
        *(uint4*)orow = *(uint4*)pk;
    }
}

// ---------------------------------------------------------------------------
// out^T GEMM: 64x64 tiles, grid 8x64 = 512 blocks = 2/CU. LDS 32 KB dbuf.
// ---------------------------------------------------------------------------
__global__ __launch_bounds__(256) void out_gemm_kernel(
    const u16* __restrict__ Wob, const u16* __restrict__ resb,
    const float* __restrict__ bo, const float* __restrict__ x,
    float* __restrict__ out)
{
    __shared__ u16 lds[16384];
    f32x4 acc[2][2];
    #pragma unroll
    for (int mt = 0; mt < 2; ++mt)
        #pragma unroll
        for (int nt = 0; nt < 2; ++nt)
            { acc[mt][nt][0]=0.f; acc[mt][nt][1]=0.f; acc[mt][nt][2]=0.f; acc[mt][nt][3]=0.f; }
    const int m0 = blockIdx.x * 64;   // c
    const int n0 = blockIdx.y * 64;   // pix
    gemm64x64_bt_mainloop(Wob, resb, m0, n0, acc, lds);

    const int tid = threadIdx.x;
    const int lane = tid & 63, quad = lane >> 4, l16 = lane & 15;
    const int wr = ((tid >> 7) & 1) * 32, wc = ((tid >> 6) & 1) * 32;
    #pragma unroll
    for (int nt = 0; nt < 2; ++nt) {
        const int pix = n0 + wc + nt * 16 + l16;
        const int b = pix >> 10, ip = pix & 1023;
        #pragma unroll
        for (int mt = 0; mt < 2; ++mt) {
            #pragma unroll
            for (int r = 0; r < 4; ++r) {
                const int c = m0 + wr + mt * 16 + quad * 4 + r;
                const size_t oidx = (((size_t)b * 512 + c) << 10) + ip;
                out[oidx] = acc[mt][nt][r] + bo[c] + x[oidx];
            }
        }
    }
}

// ---------------------------------------------------------------------------
extern "C" void kernel_launch(void* const* d_in, const int* in_sizes, int n_in,
                              void* d_out, int out_size, void* d_ws, size_t ws_size,
                              hipStream_t stream)
{
    const float* x  = (const float*)d_in[0];   // [4,512,32,32]
    const float* Wp = (const float*)d_in[1];   // [1536,512]
    const float* bp = (const float*)d_in[2];   // [1536]
    const float* Wo = (const float*)d_in[3];   // [512,512]
    const float* bo = (const float*)d_in[4];   // [512]
    float* out = (float*)d_out;

    char* ws = (char*)d_ws;
    size_t off = 0;
    auto carve = [&](size_t bytes) -> void* {
        void* ptr = ws + off;
        off += (bytes + 255) & ~(size_t)255;
        return ptr;
    };
    __hip_bfloat16* xs_bf = (__hip_bfloat16*)carve((size_t)4096 * 512 * 2);
    __hip_bfloat16* Wp_bf = (__hip_bfloat16*)carve((size_t)1536 * 512 * 2);  // Wo_bf contiguous after
    __hip_bfloat16* Wo_bf = (__hip_bfloat16*)carve((size_t)512 * 512 * 2);
    u16*            Qb    = (u16*)carve((size_t)32 * 1024 * 64 * 2);
    u16*            Kb    = (u16*)carve((size_t)32 * 1024 * 64 * 2);
    f16*            VtT   = (f16*)carve((size_t)32 * 1024 * 64 * 2);
    __hip_bfloat16* resb  = (__hip_bfloat16*)carve((size_t)4096 * 512 * 2);

    prep_kernel<<<dim3(3072), 256, 0, stream>>>(x, xs_bf, Wp, Wo, Wp_bf);
    qkv_gemm_kernel<<<dim3(32, 24), 256, 0, stream>>>(
        (const u16*)Wp_bf, (const u16*)xs_bf, bp, Qb, Kb, VtT);
    attn_kernel<<<dim3(32, 16), 256, 0, stream>>>(Qb, Kb, VtT, resb);
    out_gemm_kernel<<<dim3(8, 64), 256, 0, stream>>>(
        (const u16*)Wo_bf, (const u16*)resb, bo, x, out);
    (void)Wo_bf; (void)ws_size; (void)in_sizes; (void)n_in; (void)out_size;
}

// Round 9
// 110.083 us; speedup vs baseline: 1.2895x; 1.0115x over previous
//
#include <hip/hip_runtime.h>
#include <hip/hip_bf16.h>

typedef unsigned short u16;
typedef __attribute__((ext_vector_type(8))) short frag_ab;   // 8 bf16 (4 VGPRs)
typedef __attribute__((ext_vector_type(4))) float f32x4;     // 4 fp32 acc
typedef _Float16 f16;
typedef __attribute__((ext_vector_type(4))) _Float16 f16x4;  // 4 f16 (2 VGPRs)

#define LOG2E 1.44269504088896f

__device__ __forceinline__ float fast_exp2(float x) {
    return __builtin_amdgcn_exp2f(x);   // v_exp_f32 (D = 2^S0)
}

__device__ __forceinline__ void gload_lds16(const u16* g, u16* s) {
    __builtin_amdgcn_global_load_lds((const __attribute__((address_space(1))) void*)g,
                                     (__attribute__((address_space(3))) void*)s, 16, 0, 0);
}

// ---------------------------------------------------------------------------
// 64x128 B^T GEMM mainloop, K=512, 2-phase pipelined (R2 structure, proven).
// ---------------------------------------------------------------------------
__device__ __forceinline__ void gemm64x128_bt_mainloop(
    const u16* __restrict__ A, const u16* __restrict__ B,
    int m0, int n0, f32x4 acc[2][4], u16* lds)
{
    const int tid = threadIdx.x;
    const int lane = tid & 63, quad = lane >> 4, l16 = lane & 15;
    const int wr = ((tid >> 7) & 1) * 32;
    const int wc = ((tid >> 6) & 1) * 64;
    const int srow = tid >> 3;
    const int scol = (tid & 7) * 8;

    u16* Asb[2] = {lds, lds + 12288};
    u16* Bsb[2] = {lds + 4096, lds + 16384};

#define STAGE_128(bi, k0) do {                                                \
        u16* As_ = Asb[bi]; u16* Bs_ = Bsb[bi];                               \
        _Pragma("unroll")                                                     \
        for (int p = 0; p < 2; ++p) {                                         \
            const int r = srow + p * 32;                                      \
            gload_lds16(A + (size_t)(m0 + r) * 512 + (k0) + scol,             \
                        As_ + r * 64 + scol);                                 \
        }                                                                     \
        _Pragma("unroll")                                                     \
        for (int p = 0; p < 4; ++p) {                                         \
            const int r = srow + p * 32;                                      \
            gload_lds16(B + (size_t)(n0 + r) * 512 + (k0) + scol,             \
                        Bs_ + r * 64 + scol);                                 \
        }                                                                     \
    } while (0)

    STAGE_128(0, 0);
    __syncthreads();
    #pragma unroll
    for (int t = 0; t < 8; ++t) {
        const int cur = t & 1;
        if (t < 7) STAGE_128(cur ^ 1, (t + 1) * 64);
        u16* Asc = Asb[cur];
        u16* Bsc = Bsb[cur];
        #pragma unroll
        for (int ks = 0; ks < 2; ++ks) {
            frag_ab a[2], b[4];
            #pragma unroll
            for (int mt = 0; mt < 2; ++mt)
                a[mt] = *(const frag_ab*)(Asc + (wr + mt * 16 + l16) * 64 + ks * 32 + quad * 8);
            #pragma unroll
            for (int nt = 0; nt < 4; ++nt)
                b[nt] = *(const frag_ab*)(Bsc + (wc + nt * 16 + l16) * 64 + ks * 32 + quad * 8);
            #pragma unroll
            for (int mt = 0; mt < 2; ++mt)
                #pragma unroll
                for (int nt = 0; nt < 4; ++nt)
                    acc[mt][nt] = __builtin_amdgcn_mfma_f32_16x16x32_bf16(a[mt], b[nt], acc[mt][nt], 0, 0, 0);
        }
        if (t < 7) __syncthreads();
    }
#undef STAGE_128
}

// ---------------------------------------------------------------------------
// 64x64 B^T GEMM mainloop, K=512, same 2-phase pipeline. LDS 32 KB.
// ---------------------------------------------------------------------------
__device__ __forceinline__ void gemm64x64_bt_mainloop(
    const u16* __restrict__ A, const u16* __restrict__ B,
    int m0, int n0, f32x4 acc[2][2], u16* lds)
{
    const int tid = threadIdx.x;
    const int lane = tid & 63, quad = lane >> 4, l16 = lane & 15;
    const int wr = ((tid >> 7) & 1) * 32;
    const int wc = ((tid >> 6) & 1) * 32;
    const int srow = tid >> 3;
    const int scol = (tid & 7) * 8;

    u16* Asb[2] = {lds, lds + 8192};
    u16* Bsb[2] = {lds + 4096, lds + 12288};

#define STAGE_64(bi, k0) do {                                                 \
        u16* As_ = Asb[bi]; u16* Bs_ = Bsb[bi];                               \
        _Pragma("unroll")                                                     \
        for (int p = 0; p < 2; ++p) {                                         \
            const int r = srow + p * 32;                                      \
            gload_lds16(A + (size_t)(m0 + r) * 512 + (k0) + scol,             \
                        As_ + r * 64 + scol);                                 \
            gload_lds16(B + (size_t)(n0 + r) * 512 + (k0) + scol,             \
                        Bs_ + r * 64 + scol);                                 \
        }                                                                     \
    } while (0)

    STAGE_64(0, 0);
    __syncthreads();
    #pragma unroll
    for (int t = 0; t < 8; ++t) {
        const int cur = t & 1;
        if (t < 7) STAGE_64(cur ^ 1, (t + 1) * 64);
        u16* Asc = Asb[cur];
        u16* Bsc = Bsb[cur];
        #pragma unroll
        for (int ks = 0; ks < 2; ++ks) {
            frag_ab a[2], b[2];
            #pragma unroll
            for (int mt = 0; mt < 2; ++mt)
                a[mt] = *(const frag_ab*)(Asc + (wr + mt * 16 + l16) * 64 + ks * 32 + quad * 8);
            #pragma unroll
            for (int nt = 0; nt < 2; ++nt)
                b[nt] = *(const frag_ab*)(Bsc + (wc + nt * 16 + l16) * 64 + ks * 32 + quad * 8);
            #pragma unroll
            for (int mt = 0; mt < 2; ++mt)
                #pragma unroll
                for (int nt = 0; nt < 2; ++nt)
                    acc[mt][nt] = __builtin_amdgcn_mfma_f32_16x16x32_bf16(a[mt], b[nt], acc[mt][nt], 0, 0, 0);
        }
        if (t < 7) __syncthreads();
    }
#undef STAGE_64
}

// ---------------------------------------------------------------------------
// Fused prep: blocks [0,2048): x transpose+cast; [2048,3072): W converts.
// ---------------------------------------------------------------------------
__global__ __launch_bounds__(256) void prep_kernel(
    const float* __restrict__ x, __hip_bfloat16* __restrict__ xs_bf,
    const float* __restrict__ Wp, const float* __restrict__ Wo,
    __hip_bfloat16* __restrict__ w_bf)
{
    __shared__ float tile[32][33];
    const int tid = threadIdx.x;
    const int id = blockIdx.x;
    if (id < 2048) {
        const int i0 = (id & 31) * 32;
        const int c0 = ((id >> 5) & 15) * 32;
        const int b  = id >> 9;
        const int tx = tid & 31, ty = tid >> 5;
        const float* xp = x + ((size_t)b * 512 + c0) * 1024 + i0;
        #pragma unroll
        for (int r = ty; r < 32; r += 8)
            tile[r][tx] = xp[(size_t)r * 1024 + tx];
        __syncthreads();
        __hip_bfloat16* op = xs_bf + ((size_t)b * 1024 + i0) * 512 + c0;
        #pragma unroll
        for (int r = ty; r < 32; r += 8)
            op[(size_t)r * 512 + tx] = __float2bfloat16(tile[tx][r]);
    } else {
        const int t = (id - 2048) * 256 + tid;
        const int i4 = t * 4;
        const float* src = (i4 < 786432) ? (Wp + i4) : (Wo + (i4 - 786432));
        const float4 v = *(const float4*)src;
        ushort4 o;
        o.x = __bfloat16_as_ushort(__float2bfloat16(v.x));
        o.y = __bfloat16_as_ushort(__float2bfloat16(v.y));
        o.z = __bfloat16_as_ushort(__float2bfloat16(v.z));
        o.w = __bfloat16_as_ushort(__float2bfloat16(v.w));
        *(ushort4*)((u16*)w_bf + i4) = o;
    }
}

// ---------------------------------------------------------------------------
// qkv^T GEMM: 64-ch x 128-pix tiles, grid (32 pix-windows, 24 ch-tiles).
// ---------------------------------------------------------------------------
__global__ __launch_bounds__(256) void qkv_gemm_kernel(
    const u16* __restrict__ Wpb, const u16* __restrict__ xsb,
    const float* __restrict__ bp,
    u16* __restrict__ Qb, u16* __restrict__ Kb, f16* __restrict__ VtT)
{
    __shared__ u16 lds[24576];      // dbuf As/Bs; reused as Tr[128][72]
    f32x4 acc[2][4];
    #pragma unroll
    for (int mt = 0; mt < 2; ++mt)
        #pragma unroll
        for (int nt = 0; nt < 4; ++nt)
            { acc[mt][nt][0]=0.f; acc[mt][nt][1]=0.f; acc[mt][nt][2]=0.f; acc[mt][nt][3]=0.f; }
    const int m0 = blockIdx.y * 64;    // ch   (y: 0..23)
    const int n0 = blockIdx.x * 128;   // pix  (x: 0..31)
    gemm64x128_bt_mainloop(Wpb, xsb, m0, n0, acc, lds);

    const int tid = threadIdx.x;
    const int lane = tid & 63, quad = lane >> 4, l16 = lane & 15;
    const int wr = ((tid >> 7) & 1) * 32, wc = ((tid >> 6) & 1) * 64;
    const int h = blockIdx.y / 3, part = blockIdx.y % 3;   // block-uniform
    const int b = blockIdx.x >> 3, ipb = (blockIdx.x & 7) * 128;
    const size_t bh = (size_t)(b * 8 + h);

    if (part < 2) {
        const float scale = (part == 0) ? (0.125f * LOG2E) : 1.0f;
        __syncthreads();            // all waves done with mainloop LDS
        u16* T = lds;               // [pix 128][ch 64 pad 72]
        #pragma unroll
        for (int nt = 0; nt < 4; ++nt) {
            const int px = wc + nt * 16 + l16;
            #pragma unroll
            for (int mt = 0; mt < 2; ++mt) {
                const int cb = m0 + wr + mt * 16 + quad * 4;
                ushort4 pk;
                pk.x = __bfloat16_as_ushort(__float2bfloat16((acc[mt][nt][0] + bp[cb + 0]) * scale));
                pk.y = __bfloat16_as_ushort(__float2bfloat16((acc[mt][nt][1] + bp[cb + 1]) * scale));
                pk.z = __bfloat16_as_ushort(__float2bfloat16((acc[mt][nt][2] + bp[cb + 2]) * scale));
                pk.w = __bfloat16_as_ushort(__float2bfloat16((acc[mt][nt][3] + bp[cb + 3]) * scale));
                *(ushort4*)&T[px * 72 + wr + mt * 16 + quad * 4] = pk;
            }
        }
        __syncthreads();
        u16* dst = (part == 0 ? Qb : Kb);
        #pragma unroll
        for (int p = 0; p < 4; ++p) {
            const int row = p * 32 + (tid >> 3);
            const int ch8 = (tid & 7) * 8;
            uint4 rv = *(uint4*)&T[row * 72 + ch8];
            *(uint4*)(dst + ((bh * 1024 + ipb + row) << 6) + ch8) = rv;
        }
    } else {
        f16* dst = VtT + bh * 65536;   // [jc 128][d 64][j8 8]
        #pragma unroll
        for (int mt = 0; mt < 2; ++mt) {
            #pragma unroll
            for (int r = 0; r < 4; ++r) {
                const int d = wr + mt * 16 + quad * 4 + r;
                const float bias = bp[m0 + d];
                #pragma unroll
                for (int nt = 0; nt < 4; ++nt) {
                    const int j = ipb + wc + nt * 16 + l16;
                    dst[(size_t)(j >> 3) * 512 + d * 8 + (j & 7)] =
                        (f16)(acc[mt][nt][r] + bias);
                }
            }
        }
    }
}

// ---------------------------------------------------------------------------
// Attention v9: v4 geometry (proven optimum: 512 blocks x 4 waves, disjoint
// 32-j per wave, (256,2), 2-deep prefetch) with PHASE-BATCHED inner step:
// instead of 4x(QK -> exp -> PV) serial chains per jt, run three long
// homogeneous phases — all 16 QK MFMAs, then all softmax VALU/trans, then
// all 32 PV MFMAs. Each phase is internally independent (back-to-back
// issue); co-resident waves land in different phases (role diversity) so
// MFMA and trans pipes overlap across waves, and setprio has something to
// arbitrate (T5 prereq per m218b). Register cost (st[4][2], p[4][2]) paid
// by reverting R8's null 3-deep prefetch to 2-deep; ~220 VGPR < 256 cap.
// ---------------------------------------------------------------------------
__global__ __launch_bounds__(256, 2) void attn_kernel(
    const u16* __restrict__ Qb, const u16* __restrict__ Kb,
    const f16* __restrict__ VtT, __hip_bfloat16* __restrict__ resb)
{
    __shared__ float Opart[4][32][68];    // 34.8 KB combine staging
    __shared__ float Lpart[4][4][16];     // 1 KB [w][ig][i]
    const int bh = blockIdx.x;
    const int it = blockIdx.y;            // 64-row i tile, 0..15
    const int tid = threadIdx.x;
    const int w = tid >> 6, lane = tid & 63, quad = lane >> 4, l16 = lane & 15;

    const u16* Qp = Qb + (size_t)bh * 65536;
    const u16* Kp = Kb + (size_t)bh * 65536;
    const f16* Vp = VtT + (size_t)bh * 65536;

    frag_ab bq[4][2];
    #pragma unroll
    for (int ig = 0; ig < 4; ++ig) {
        const u16* qptr = Qp + (size_t)(it * 64 + ig * 16 + l16) * 64 + quad * 8;
        bq[ig][0] = *(const frag_ab*)(qptr);
        bq[ig][1] = *(const frag_ab*)(qptr + 32);
    }

    f32x4 o[4][4];
    #pragma unroll
    for (int ig = 0; ig < 4; ++ig)
        #pragma unroll
        for (int dt = 0; dt < 4; ++dt)
            { o[ig][dt][0]=0.f; o[ig][dt][1]=0.f; o[ig][dt][2]=0.f; o[ig][dt][3]=0.f; }
    float l_acc[4] = {0.f, 0.f, 0.f, 0.f};

    const u16* kbase = Kp + (size_t)(w * 32 + l16) * 64 + quad * 8;
    const f16* vbase = Vp + (size_t)(w * 4 + (quad >> 1)) * 512 + l16 * 8 + (quad & 1) * 4;

#define LOADKV(JT, KA, VA) do {                                              \
        const u16* kp_ = kbase + (size_t)(JT) * 8192;                        \
        KA[0][0] = *(const frag_ab*)(kp_);                                   \
        KA[0][1] = *(const frag_ab*)(kp_ + 32);                              \
        KA[1][0] = *(const frag_ab*)(kp_ + 1024);                            \
        KA[1][1] = *(const frag_ab*)(kp_ + 1056);                            \
        const f16* vp_ = vbase + (size_t)(JT) * 8192;                        \
        _Pragma("unroll")                                                    \
        for (int dt_ = 0; dt_ < 4; ++dt_) {                                  \
            VA[dt_][0] = *(const f16x4*)(vp_ + dt_ * 128);                   \
            VA[dt_][1] = *(const f16x4*)(vp_ + 1024 + dt_ * 128);            \
        }                                                                    \
    } while (0)

// Phase-batched: QK x16 | softmax x4ig | PV x32, each internally independent.
#define COMPUTE(KA, VA) do {                                                 \
        f32x4 st0[4], st1[4];                                                \
        __builtin_amdgcn_s_setprio(1);                                       \
        _Pragma("unroll")                                                    \
        for (int ig = 0; ig < 4; ++ig) {                                     \
            st0[ig][0]=0.f; st0[ig][1]=0.f; st0[ig][2]=0.f; st0[ig][3]=0.f;  \
            st1[ig][0]=0.f; st1[ig][1]=0.f; st1[ig][2]=0.f; st1[ig][3]=0.f;  \
            st0[ig] = __builtin_amdgcn_mfma_f32_16x16x32_bf16(KA[0][0], bq[ig][0], st0[ig], 0, 0, 0); \
            st0[ig] = __builtin_amdgcn_mfma_f32_16x16x32_bf16(KA[0][1], bq[ig][1], st0[ig], 0, 0, 0); \
            st1[ig] = __builtin_amdgcn_mfma_f32_16x16x32_bf16(KA[1][0], bq[ig][0], st1[ig], 0, 0, 0); \
            st1[ig] = __builtin_amdgcn_mfma_f32_16x16x32_bf16(KA[1][1], bq[ig][1], st1[ig], 0, 0, 0); \
        }                                                                    \
        __builtin_amdgcn_s_setprio(0);                                       \
        f16x4 p0[4], p1[4];                                                  \
        _Pragma("unroll")                                                    \
        for (int ig = 0; ig < 4; ++ig) {                                     \
            float s = 0.f;                                                   \
            _Pragma("unroll")                                                \
            for (int r = 0; r < 4; ++r) {                                    \
                const float e0 = fast_exp2(st0[ig][r]);                      \
                const float e1 = fast_exp2(st1[ig][r]);                      \
                s += e0 + e1;                                                \
                p0[ig][r] = (f16)e0;                                         \
                p1[ig][r] = (f16)e1;                                         \
            }                                                                \
            l_acc[ig] += s;                                                  \
        }                                                                    \
        __builtin_amdgcn_s_setprio(1);                                       \
        _Pragma("unroll")                                                    \
        for (int ig = 0; ig < 4; ++ig) {                                     \
            _Pragma("unroll")                                                \
            for (int dt = 0; dt < 4; ++dt) {                                 \
                o[ig][dt] = __builtin_amdgcn_mfma_f32_16x16x16f16(VA[dt][0], p0[ig], o[ig][dt], 0, 0, 0); \
                o[ig][dt] = __builtin_amdgcn_mfma_f32_16x16x16f16(VA[dt][1], p1[ig], o[ig][dt], 0, 0, 0); \
            }                                                                \
        }                                                                    \
        __builtin_amdgcn_s_setprio(0);                                       \
    } while (0)

    frag_ab ka0[2][2], ka1[2][2];
    f16x4 va0[4][2], va1[4][2];
    LOADKV(0, ka0, va0);
    #pragma unroll
    for (int jt = 0; jt < 8; jt += 2) {
        LOADKV(jt + 1, ka1, va1);
        COMPUTE(ka0, va0);
        if (jt < 6)
            LOADKV(jt + 2, ka0, va0);
        COMPUTE(ka1, va1);
    }
#undef LOADKV
#undef COMPUTE

    #pragma unroll
    for (int ig = 0; ig < 4; ++ig) {
        l_acc[ig] += __shfl_xor(l_acc[ig], 16);
        l_acc[ig] += __shfl_xor(l_acc[ig], 32);
    }
    if (lane < 16) {
        #pragma unroll
        for (int ig = 0; ig < 4; ++ig)
            Lpart[w][ig][lane] = l_acc[ig];
    }

    const int bb = bh >> 3, hh = bh & 7;
    const int il = tid >> 3, d0 = (tid & 7) * 8;
    #pragma unroll
    for (int ph = 0; ph < 2; ++ph) {
        __syncthreads();
        #pragma unroll
        for (int g = 0; g < 2; ++g) {
            const int ig = ph * 2 + g;
            #pragma unroll
            for (int dt = 0; dt < 4; ++dt)
                *(f32x4*)&Opart[w][g * 16 + l16][dt * 16 + quad * 4] = o[ig][dt];
        }
        __syncthreads();
        f32x4 sa = *(const f32x4*)&Opart[0][il][d0];
        f32x4 sb = *(const f32x4*)&Opart[0][il][d0 + 4];
        #pragma unroll
        for (int ww = 1; ww < 4; ++ww) {
            sa += *(const f32x4*)&Opart[ww][il][d0];
            sb += *(const f32x4*)&Opart[ww][il][d0 + 4];
        }
        const int ig = ph * 2 + (il >> 4);
        const float linv = 1.f / (Lpart[0][ig][il & 15] + Lpart[1][ig][il & 15] +
                                  Lpart[2][ig][il & 15] + Lpart[3][ig][il & 15]);
        u16 pk[8];
        #pragma unroll
        for (int e = 0; e < 4; ++e) {
            pk[e]     = __bfloat16_as_ushort(__float2bfloat16(sa[e] * linv));
            pk[e + 4] = __bfloat16_as_ushort(__float2bfloat16(sb[e] * linv));
        }
        u16* orow = (u16*)resb +
            ((size_t)(bb * 1024 + it * 64 + ph * 32 + il)) * 512 + hh * 64 + d0;
        *(uint4*)orow = *(uint4*)pk;
    }
}

// ---------------------------------------------------------------------------
// out^T GEMM: 64x64 tiles, grid 8x64 = 512 blocks = 2/CU. LDS 32 KB dbuf.
// ---------------------------------------------------------------------------
__global__ __launch_bounds__(256) void out_gemm_kernel(
    const u16* __restrict__ Wob, const u16* __restrict__ resb,
    const float* __restrict__ bo, const float* __restrict__ x,
    float* __restrict__ out)
{
    __shared__ u16 lds[16384];
    f32x4 acc[2][2];
    #pragma unroll
    for (int mt = 0; mt < 2; ++mt)
        #pragma unroll
        for (int nt = 0; nt < 2; ++nt)
            { acc[mt][nt][0]=0.f; acc[mt][nt][1]=0.f; acc[mt][nt][2]=0.f; acc[mt][nt][3]=0.f; }
    const int m0 = blockIdx.x * 64;   // c
    const int n0 = blockIdx.y * 64;   // pix
    gemm64x64_bt_mainloop(Wob, resb, m0, n0, acc, lds);

    const int tid = threadIdx.x;
    const int lane = tid & 63, quad = lane >> 4, l16 = lane & 15;
    const int wr = ((tid >> 7) & 1) * 32, wc = ((tid >> 6) & 1) * 32;
    #pragma unroll
    for (int nt = 0; nt < 2; ++nt) {
        const int pix = n0 + wc + nt * 16 + l16;
        const int b = pix >> 10, ip = pix & 1023;
        #pragma unroll
        for (int mt = 0; mt < 2; ++mt) {
            #pragma unroll
            for (int r = 0; r < 4; ++r) {
                const int c = m0 + wr + mt * 16 + quad * 4 + r;
                const size_t oidx = (((size_t)b * 512 + c) << 10) + ip;
                out[oidx] = acc[mt][nt][r] + bo[c] + x[oidx];
            }
        }
    }
}

// ---------------------------------------------------------------------------
extern "C" void kernel_launch(void* const* d_in, const int* in_sizes, int n_in,
                              void* d_out, int out_size, void* d_ws, size_t ws_size,
                              hipStream_t stream)
{
    const float* x  = (const float*)d_in[0];   // [4,512,32,32]
    const float* Wp = (const float*)d_in[1];   // [1536,512]
    const float* bp = (const float*)d_in[2];   // [1536]
    const float* Wo = (const float*)d_in[3];   // [512,512]
    const float* bo = (const float*)d_in[4];   // [512]
    float* out = (float*)d_out;

    char* ws = (char*)d_ws;
    size_t off = 0;
    auto carve = [&](size_t bytes) -> void* {
        void* ptr = ws + off;
        off += (bytes + 255) & ~(size_t)255;
        return ptr;
    };
    __hip_bfloat16* xs_bf = (__hip_bfloat16*)carve((size_t)4096 * 512 * 2);
    __hip_bfloat16* Wp_bf = (__hip_bfloat16*)carve((size_t)1536 * 512 * 2);  // Wo_bf contiguous after
    __hip_bfloat16* Wo_bf = (__hip_bfloat16*)carve((size_t)512 * 512 * 2);
    u16*            Qb    = (u16*)carve((size_t)32 * 1024 * 64 * 2);
    u16*            Kb    = (u16*)carve((size_t)32 * 1024 * 64 * 2);
    f16*            VtT   = (f16*)carve((size_t)32 * 1024 * 64 * 2);
    __hip_bfloat16* resb  = (__hip_bfloat16*)carve((size_t)4096 * 512 * 2);

    prep_kernel<<<dim3(3072), 256, 0, stream>>>(x, xs_bf, Wp, Wo, Wp_bf);
    qkv_gemm_kernel<<<dim3(32, 24), 256, 0, stream>>>(
        (const u16*)Wp_bf, (const u16*)xs_bf, bp, Qb, Kb, VtT);
    attn_kernel<<<dim3(32, 16), 256, 0, stream>>>(Qb, Kb, VtT, resb);
    out_gemm_kernel<<<dim3(8, 64), 256, 0, stream>>>(
        (const u16*)Wo_bf, (const u16*)resb, bo, x, out);
    (void)Wo_bf; (void)ws_size; (void)in_sizes; (void)n_in; (void)out_size;
}